// Round 1
// baseline (701.189 us; speedup 1.0000x reference)
//
#include <hip/hip_runtime.h>

// out[B=1024, O=8192] = x[B, I=16384] @ (W*mask)[O, I]^T + bias[O]
// Phase 1: convert W*mask -> bf16 (ws), x -> bf16 (ws).
// Phase 2: bf16 MFMA GEMM (m97-style 128x128 tile, BK=64, global_load_lds w16).

#define IN_DIM 16384
#define OUT_DIM 8192
#define BATCH 1024

#define BM 128
#define BN 128
#define BK 64
#define NKSTEP (IN_DIM / BK)

typedef __attribute__((ext_vector_type(8))) short bf16x8;
typedef __attribute__((ext_vector_type(4))) float f32x4;
typedef __attribute__((ext_vector_type(4))) unsigned short u16x4;

__device__ __forceinline__ unsigned short f2bf(float f) {
  // round-to-nearest-even f32 -> bf16 (inputs finite, no NaN handling needed)
  unsigned int u = __float_as_uint(f);
  return (unsigned short)((u + 0x7fffu + ((u >> 16) & 1u)) >> 16);
}

#define GLOAD_LDS16(g, l)                                         \
  __builtin_amdgcn_global_load_lds(                               \
      (const __attribute__((address_space(1))) void*)(g),         \
      (__attribute__((address_space(3))) void*)(l), 16, 0, 0)

__global__ __launch_bounds__(256) void prep_w_kernel(
    const float4* __restrict__ w, const float4* __restrict__ m,
    u16x4* __restrict__ out, int n4) {
  int i = blockIdx.x * blockDim.x + threadIdx.x;
  int stride = gridDim.x * blockDim.x;
  for (; i < n4; i += stride) {
    float4 wv = w[i];
    float4 mv = m[i];
    u16x4 o;
    o.x = f2bf(wv.x * mv.x);
    o.y = f2bf(wv.y * mv.y);
    o.z = f2bf(wv.z * mv.z);
    o.w = f2bf(wv.w * mv.w);
    out[i] = o;
  }
}

__global__ __launch_bounds__(256) void prep_x_kernel(
    const float4* __restrict__ x, u16x4* __restrict__ out, int n4) {
  int i = blockIdx.x * blockDim.x + threadIdx.x;
  int stride = gridDim.x * blockDim.x;
  for (; i < n4; i += stride) {
    float4 v = x[i];
    u16x4 o;
    o.x = f2bf(v.x);
    o.y = f2bf(v.y);
    o.z = f2bf(v.z);
    o.w = f2bf(v.w);
    out[i] = o;
  }
}

// FUSED=0: A/B are pre-converted bf16 in ws, staged via global_load_lds.
// FUSED=1: convert x and W*mask f32 -> bf16 in-kernel (fallback if ws too small).
template <int FUSED>
__global__ __launch_bounds__(256) void gemm_kernel(
    const short* __restrict__ Ab, const short* __restrict__ Bb,
    const float* __restrict__ X, const float* __restrict__ W,
    const float* __restrict__ Msk, const float* __restrict__ bias,
    float* __restrict__ out) {
  __shared__ short As[BM * BK];
  __shared__ short Bs[BN * BK];

  const int tid = threadIdx.x;
  const int lane = tid & 63;
  const int wv = tid >> 6;      // wave 0..3
  const int wm = wv >> 1;       // wave row 0..1 (64 rows each)
  const int wn = wv & 1;        // wave col 0..1 (64 cols each)
  const int fr = lane & 15;     // fragment row/col index
  const int fq = lane >> 4;     // 0..3

  const int bid = blockIdx.x;
  const int mt = bid & 7;       // M-tiles fastest: 8 consecutive wgs share a B-panel
  const int nt = bid >> 3;
  const int row0 = mt * BM;
  const int col0 = nt * BN;

  f32x4 acc[4][4];
#pragma unroll
  for (int i = 0; i < 4; ++i)
#pragma unroll
    for (int j = 0; j < 4; ++j) acc[i][j] = (f32x4)0.f;

  // global_load_lds staging geometry: per issue, each wave writes 1024B
  // = 8 rows x (BK*2=128B); lane l -> row l>>3, 16B chunk (l&7)*16.
  const int srow = lane >> 3;
  const int skof = (lane & 7) * 8;  // bf16 elements

  for (int kt = 0; kt < NKSTEP; ++kt) {
    const int k0 = kt * BK;
    __syncthreads();  // previous compute done before LDS overwrite
    if constexpr (!FUSED) {
#pragma unroll
      for (int is = 0; is < 4; ++is) {
        const int rbase = is * 32 + wv * 8;      // wave-uniform row base
        const int r = rbase + srow;
        const short* ga = Ab + (size_t)(row0 + r) * IN_DIM + k0 + skof;
        const short* gb = Bb + (size_t)(col0 + r) * IN_DIM + k0 + skof;
        short* la = As + rbase * BK;             // wave-uniform LDS base
        short* lb = Bs + rbase * BK;
        GLOAD_LDS16(ga, la);
        GLOAD_LDS16(gb, lb);
      }
    } else {
#pragma unroll
      for (int is = 0; is < 4; ++is) {
        const int e = (is * 256 + tid) * 8;  // 8 contiguous bf16 along k
        const int r = e >> 6;
        const int kk = e & 63;
        {
          const float* src = X + (size_t)(row0 + r) * IN_DIM + k0 + kk;
          float4 a0 = *(const float4*)src;
          float4 a1 = *(const float4*)(src + 4);
          bf16x8 v;
          v[0] = (short)f2bf(a0.x); v[1] = (short)f2bf(a0.y);
          v[2] = (short)f2bf(a0.z); v[3] = (short)f2bf(a0.w);
          v[4] = (short)f2bf(a1.x); v[5] = (short)f2bf(a1.y);
          v[6] = (short)f2bf(a1.z); v[7] = (short)f2bf(a1.w);
          *(bf16x8*)&As[r * BK + kk] = v;
        }
        {
          const float* sw = W + (size_t)(col0 + r) * IN_DIM + k0 + kk;
          const float* sm = Msk + (size_t)(col0 + r) * IN_DIM + k0 + kk;
          float4 w0 = *(const float4*)sw;
          float4 w1 = *(const float4*)(sw + 4);
          float4 m0 = *(const float4*)sm;
          float4 m1 = *(const float4*)(sm + 4);
          bf16x8 v;
          v[0] = (short)f2bf(w0.x * m0.x); v[1] = (short)f2bf(w0.y * m0.y);
          v[2] = (short)f2bf(w0.z * m0.z); v[3] = (short)f2bf(w0.w * m0.w);
          v[4] = (short)f2bf(w1.x * m1.x); v[5] = (short)f2bf(w1.y * m1.y);
          v[6] = (short)f2bf(w1.z * m1.z); v[7] = (short)f2bf(w1.w * m1.w);
          *(bf16x8*)&Bs[r * BK + kk] = v;
        }
      }
    }
    __syncthreads();  // compiler drains vmcnt before barrier

#pragma unroll
    for (int ks = 0; ks < 2; ++ks) {
      bf16x8 af[4], bf[4];
#pragma unroll
      for (int i = 0; i < 4; ++i)
        af[i] = *(const bf16x8*)&As[(wm * 64 + i * 16 + fr) * BK + ks * 32 + fq * 8];
#pragma unroll
      for (int j = 0; j < 4; ++j)
        bf[j] = *(const bf16x8*)&Bs[(wn * 64 + j * 16 + fr) * BK + ks * 32 + fq * 8];
#pragma unroll
      for (int i = 0; i < 4; ++i)
#pragma unroll
        for (int j = 0; j < 4; ++j)
          acc[i][j] = __builtin_amdgcn_mfma_f32_16x16x32_bf16(af[i], bf[j],
                                                              acc[i][j], 0, 0, 0);
    }
  }

  // Epilogue: C/D layout col = lane&15, row = (lane>>4)*4 + reg (m89/m91)
#pragma unroll
  for (int j = 0; j < 4; ++j) {
    const int c = col0 + wn * 64 + j * 16 + fr;
    const float bv = bias[c];
#pragma unroll
    for (int i = 0; i < 4; ++i) {
      const int rb = row0 + wm * 64 + i * 16 + fq * 4;
#pragma unroll
      for (int t = 0; t < 4; ++t)
        out[(size_t)(rb + t) * OUT_DIM + c] = acc[i][j][t] + bv;
    }
  }
}

extern "C" void kernel_launch(void* const* d_in, const int* in_sizes, int n_in,
                              void* d_out, int out_size, void* d_ws, size_t ws_size,
                              hipStream_t stream) {
  const float* x = (const float*)d_in[0];
  const float* w = (const float*)d_in[1];
  const float* bias = (const float*)d_in[2];
  const float* mask = (const float*)d_in[3];
  float* out = (float*)d_out;

  const size_t wm_elems = (size_t)OUT_DIM * IN_DIM;  // 134,217,728
  const size_t xb_elems = (size_t)BATCH * IN_DIM;    // 16,777,216
  const size_t need = (wm_elems + xb_elems) * sizeof(short);  // 288 MB

  dim3 block(256);
  dim3 grid_gemm((BATCH / BM) * (OUT_DIM / BN));  // 8 * 64 = 512

  if (ws_size >= need) {
    short* wmb = (short*)d_ws;
    short* xbb = wmb + wm_elems;
    hipLaunchKernelGGL(prep_w_kernel, dim3(2048), block, 0, stream,
                       (const float4*)w, (const float4*)mask, (u16x4*)wmb,
                       (int)(wm_elems / 4));
    hipLaunchKernelGGL(prep_x_kernel, dim3(512), block, 0, stream,
                       (const float4*)x, (u16x4*)xbb, (int)(xb_elems / 4));
    hipLaunchKernelGGL((gemm_kernel<0>), grid_gemm, block, 0, stream,
                       xbb, wmb, (const float*)nullptr, (const float*)nullptr,
                       (const float*)nullptr, bias, out);
  } else {
    hipLaunchKernelGGL((gemm_kernel<1>), grid_gemm, block, 0, stream,
                       (const short*)nullptr, (const short*)nullptr, x, w, mask,
                       bias, out);
  }
}